// Round 14
// baseline (99.583 us; speedup 1.0000x reference)
//
#include <hip/hip_runtime.h>

// LIF neuron scan: v = v*0.5 + x[t]; s = (v - 0.5 > 0); v -= s*0.5
// Round 13 -> 14: PHASE SPLIT ACROSS KERNELS. R13 (11 blocks/CU, load-latency
// hidden) == R11 (6 blocks/CU) == ~90us: occupancy/latency were not the
// limiter. Accounting: read 26-33us + write 29us + stage/walk ~25us SERIALIZED
// = ~90us -- the per-CU phases are barrier-phase-locked, memory idles during
// walks. Fix: two kernels, each a single whole-GPU stream:
//   K1 lif_walk:  coalesced read -> LDS -> serial walk -> 16B/row packed bits
//                 to d_ws (8.4MB). Read-dominated -> ~read ceiling.
//   K2 lif_expand: bits (L2/L3-hit) -> nibble expand -> pure coalesced f4
//                 stores. Fill-like (fill measured 7 TB/s @ 10% occupancy).
// Cross-kernel visibility on one stream is guaranteed. Fallback: R13 single
// kernel if ws_size < n_rows*16 (deterministic).

#define T_STEPS 100
#define T_VEC   25      // f4 per row in global
#define ROWS    64      // rows per block == blockDim.x (one wave), K1
#define CA      12      // pass-A f4 chunks (48 steps)
#define CB      13      // pass-B f4 chunks (52 steps)
#define LSTRIDE 13      // K1 tile row stride in f4
#define DECAY   0.5f
#define VTH     0.5f

typedef float vfloat4 __attribute__((ext_vector_type(4)));

// ---------------- K1: coalesced load -> LDS -> walk -> packed bits ----------
__global__ __launch_bounds__(64, 3) void lif_walk(const float* __restrict__ x,
                                                  uint4* __restrict__ bitsg,
                                                  int n_rows) {
    __shared__ vfloat4 tile[ROWS * LSTRIDE];   // 13,312 B

    const int lane = threadIdx.x;
    const int row0 = blockIdx.x * ROWS;
    const int gf0 = row0 * T_VEC;
    const int total_f4 = n_rows * T_VEC;

    const vfloat4* __restrict__ xb = reinterpret_cast<const vfloat4*>(x);
    const vfloat4 vzero = {0.0f, 0.0f, 0.0f, 0.0f};

    // Pass A stage: coalesced loads (64 rows x 12 f4) -> tile
    {
        vfloat4 st[CA];
        #pragma unroll
        for (int k = 0; k < CA; ++k) {
            int f = k * 64 + lane;                   // 0..767
            int r = f / CA, c = f % CA;
            int g = gf0 + r * T_VEC + c;
            st[k] = (g < total_f4) ? xb[g] : vzero;
        }
        #pragma unroll
        for (int k = 0; k < CA; ++k) {
            int f = k * 64 + lane;
            int r = f / CA, c = f % CA;
            tile[r * LSTRIDE + c] = st[k];
        }
    }
    __syncthreads();   // stage-A writes visible before walk-A reads

    // Pass B loads issued now; latency hides under pass-A walk
    vfloat4 sb[CB];
    #pragma unroll
    for (int k = 0; k < CB; ++k) {
        int f = k * 64 + lane;                       // 0..831
        int r = f / CB, c = f % CB;
        int g = gf0 + r * T_VEC + CA + c;
        sb[k] = (g < total_f4) ? xb[g] : vzero;
    }
    __builtin_amdgcn_sched_barrier(0);               // pin: loads issue first

    // Walk pass A: 48 serial steps, pack bits
    unsigned int pk0 = 0, pk1 = 0, pk2 = 0, pk3 = 0;
    float v = 0.0f;
    #pragma unroll
    for (int c = 0; c < CA; ++c) {
        vfloat4 xs = tile[lane * LSTRIDE + c];
        #pragma unroll
        for (int k = 0; k < 4; ++k) {
            // v*0.5 exact (pow2); conditional -0.5 exact -> bitwise == ref.
            v = v * DECAY + xs[k];
            bool s = (v - VTH > 0.0f);
            v -= s ? VTH : 0.0f;
            unsigned int bit = s ? 1u : 0u;
            const int b = c * 4 + k;                 // 0..47
            if (b < 32) pk0 |= bit << b;
            else        pk1 |= bit << (b - 32);
        }
    }
    __syncthreads();   // WAR: walk-A reads done before stage-B overwrites

    // Pass B stage
    #pragma unroll
    for (int k = 0; k < CB; ++k) {
        int f = k * 64 + lane;
        int r = f / CB, c = f % CB;
        tile[r * LSTRIDE + c] = sb[k];
    }
    __syncthreads();   // RAW: stage-B writes before walk-B reads

    // Walk pass B: 52 serial steps
    #pragma unroll
    for (int c = 0; c < CB; ++c) {
        vfloat4 xs = tile[lane * LSTRIDE + c];
        #pragma unroll
        for (int k = 0; k < 4; ++k) {
            v = v * DECAY + xs[k];
            bool s = (v - VTH > 0.0f);
            v -= s ? VTH : 0.0f;
            unsigned int bit = s ? 1u : 0u;
            const int b = 48 + c * 4 + k;            // 48..99
            if (b < 64)      pk1 |= bit << (b - 32);
            else if (b < 96) pk2 |= bit << (b - 64);
            else             pk3 |= bit << (b - 96);
        }
    }

    // Coalesced 16B/row bits store (rows consecutive -> 1KB per wave store)
    if (row0 + lane < n_rows) {
        uint4 w; w.x = pk0; w.y = pk1; w.z = pk2; w.w = pk3;
        bitsg[row0 + lane] = w;
    }
}

// ---------------- K2: bits -> expand -> pure coalesced f4 stores ------------
__global__ __launch_bounds__(256) void lif_expand(const unsigned int* __restrict__ bw,
                                                  vfloat4* __restrict__ ob,
                                                  int total_f4, int nthreads) {
    const int gtid = blockIdx.x * 256 + threadIdx.x;
    #pragma unroll
    for (int i = 0; i < T_VEC; ++i) {
        int f = i * nthreads + gtid;         // device-wide coalesced sweep
        if (f < total_f4) {
            int r  = f / T_VEC;              // magic-mul
            int c4 = f % T_VEC;
            unsigned int word = bw[r * 4 + (c4 >> 3)];   // L1/L2-served
            unsigned int nib = (word >> ((c4 & 7) * 4)) & 0xFu;
            vfloat4 s;
            s.x = (nib & 1u) ? 1.0f : 0.0f;
            s.y = (nib & 2u) ? 1.0f : 0.0f;
            s.z = (nib & 4u) ? 1.0f : 0.0f;
            s.w = (nib & 8u) ? 1.0f : 0.0f;
            ob[f] = s;
        }
    }
}

// ---------------- Fallback: R13 single kernel (ws too small) ----------------
__global__ __launch_bounds__(64, 3) void lif_kernel(const float* __restrict__ x,
                                                    float* __restrict__ out,
                                                    int n_rows) {
    __shared__ vfloat4 tile[ROWS * LSTRIDE];
    __shared__ unsigned int bits[ROWS * 4];

    const int lane = threadIdx.x;
    const int row0 = blockIdx.x * ROWS;
    const int gf0 = row0 * T_VEC;
    const int total_f4 = n_rows * T_VEC;

    const vfloat4* __restrict__ xb = reinterpret_cast<const vfloat4*>(x);
    const vfloat4 vzero = {0.0f, 0.0f, 0.0f, 0.0f};

    {
        vfloat4 st[CA];
        #pragma unroll
        for (int k = 0; k < CA; ++k) {
            int f = k * 64 + lane;
            int r = f / CA, c = f % CA;
            int g = gf0 + r * T_VEC + c;
            st[k] = (g < total_f4) ? xb[g] : vzero;
        }
        #pragma unroll
        for (int k = 0; k < CA; ++k) {
            int f = k * 64 + lane;
            int r = f / CA, c = f % CA;
            tile[r * LSTRIDE + c] = st[k];
        }
    }
    __syncthreads();

    vfloat4 sb[CB];
    #pragma unroll
    for (int k = 0; k < CB; ++k) {
        int f = k * 64 + lane;
        int r = f / CB, c = f % CB;
        int g = gf0 + r * T_VEC + CA + c;
        sb[k] = (g < total_f4) ? xb[g] : vzero;
    }
    __builtin_amdgcn_sched_barrier(0);

    unsigned int pk0 = 0, pk1 = 0, pk2 = 0, pk3 = 0;
    float v = 0.0f;
    #pragma unroll
    for (int c = 0; c < CA; ++c) {
        vfloat4 xs = tile[lane * LSTRIDE + c];
        #pragma unroll
        for (int k = 0; k < 4; ++k) {
            v = v * DECAY + xs[k];
            bool s = (v - VTH > 0.0f);
            v -= s ? VTH : 0.0f;
            unsigned int bit = s ? 1u : 0u;
            const int b = c * 4 + k;
            if (b < 32) pk0 |= bit << b;
            else        pk1 |= bit << (b - 32);
        }
    }
    __syncthreads();

    #pragma unroll
    for (int k = 0; k < CB; ++k) {
        int f = k * 64 + lane;
        int r = f / CB, c = f % CB;
        tile[r * LSTRIDE + c] = sb[k];
    }
    __syncthreads();

    #pragma unroll
    for (int c = 0; c < CB; ++c) {
        vfloat4 xs = tile[lane * LSTRIDE + c];
        #pragma unroll
        for (int k = 0; k < 4; ++k) {
            v = v * DECAY + xs[k];
            bool s = (v - VTH > 0.0f);
            v -= s ? VTH : 0.0f;
            unsigned int bit = s ? 1u : 0u;
            const int b = 48 + c * 4 + k;
            if (b < 64)      pk1 |= bit << (b - 32);
            else if (b < 96) pk2 |= bit << (b - 64);
            else             pk3 |= bit << (b - 96);
        }
    }

    {
        uint4 w; w.x = pk0; w.y = pk1; w.z = pk2; w.w = pk3;
        reinterpret_cast<uint4*>(bits)[lane] = w;
    }
    __syncthreads();

    vfloat4* __restrict__ ob = reinterpret_cast<vfloat4*>(out);
    #pragma unroll
    for (int i = 0; i < T_VEC; ++i) {
        int f = i * 64 + lane;
        int g = gf0 + f;
        if (g < total_f4) {
            int r  = f / T_VEC;
            int c4 = f % T_VEC;
            unsigned int word = bits[r * 4 + (c4 >> 3)];
            unsigned int nib = (word >> ((c4 & 7) * 4)) & 0xFu;
            vfloat4 s;
            s.x = (nib & 1u) ? 1.0f : 0.0f;
            s.y = (nib & 2u) ? 1.0f : 0.0f;
            s.z = (nib & 4u) ? 1.0f : 0.0f;
            s.w = (nib & 8u) ? 1.0f : 0.0f;
            ob[g] = s;
        }
    }
}

extern "C" void kernel_launch(void* const* d_in, const int* in_sizes, int n_in,
                              void* d_out, int out_size, void* d_ws, size_t ws_size,
                              hipStream_t stream) {
    const float* x = (const float*)d_in[0];
    float* out = (float*)d_out;

    int n_rows = in_sizes[0] / T_STEPS;              // 32 * 16384 = 524288
    int total_f4 = n_rows * T_VEC;
    int grid1 = (n_rows + ROWS - 1) / ROWS;          // 8192

    size_t need = (size_t)n_rows * 16;               // 8.4 MB of packed bits
    if (ws_size >= need) {
        int nthreads_goal = (total_f4 + T_VEC - 1) / T_VEC;      // 524288
        int grid2 = (nthreads_goal + 255) / 256;                 // 2048
        int nthreads = grid2 * 256;
        lif_walk<<<grid1, ROWS, 0, stream>>>(x, (uint4*)d_ws, n_rows);
        lif_expand<<<grid2, 256, 0, stream>>>((const unsigned int*)d_ws,
                                              (vfloat4*)out, total_f4, nthreads);
    } else {
        lif_kernel<<<grid1, ROWS, 0, stream>>>(x, out, n_rows);
    }
}

// Round 15
// 96.110 us; speedup vs baseline: 1.0361x; 1.0361x over previous
//
#include <hip/hip_runtime.h>

// LIF neuron scan: v = v*0.5 + x[t]; s = (v - 0.5 > 0); v -= s*0.5
// Round 14 -> 15: BREAK THE PHASE LOCK. Evidence: R13 fused (91.3us) ==
// R11 (89.5) == R14 split (99.6 = phase sum + overhead): load/walk/store
// phases never overlap -- all co-resident waves run the same code in
// lock-step, so the whole GPU alternates {mem burst | VALU burst} and the
// HBM duty cycle is ~50%. Fix: persistent waves, grid-stride over 32-row
// tiles, 1-tile lookahead pipeline:
//   issue loads(t+1)->regs  (pinned first by sched_barrier)
//   walk(t) from LDS        (serial 100 steps, lanes 0-31)
//   expand+store(t)         (13 coalesced 1KB stores)
//   ds_write regs->LDS      (compiler inserts its own counted vmcnt)
// A wave always has ~13KB of loads in flight while walking/storing ->
// continuous HBM issue. Single 12.8KB tile (staging regs = 2nd buffer)
// + 512B bits = 13.3KB -> 12 blocks/CU. All LDS hazards are in-wave
// (wave-private tile, in-order DS pipe); sched_barrier(0) pins emission
// order at phase boundaries (R12 lesson); ZERO __syncthreads.

#define T_STEPS 100
#define T_VEC   25                 // f4 per row
#define TROWS   32                 // rows per tile
#define TF4     (TROWS * T_VEC)    // 800 f4 per tile (12.8 KB)
#define NLD     13                 // ceil(800/64) mem instrs per tile
#define GRID    3072               // 12 blocks/CU * 256 CU
#define DECAY   0.5f
#define VTH     0.5f

typedef float vfloat4 __attribute__((ext_vector_type(4)));

__global__ __launch_bounds__(64) void lif_pipe(const float* __restrict__ x,
                                               float* __restrict__ out,
                                               int n_rows) {
    __shared__ vfloat4 tile[TF4];       // 12,800 B
    __shared__ uint4   bitsbuf[TROWS];  //    512 B -> 13,312 total

    const int lane = threadIdx.x;
    const int ntiles = (n_rows + TROWS - 1) / TROWS;   // 16384
    const int total_f4 = n_rows * T_VEC;
    const vfloat4* __restrict__ xb = reinterpret_cast<const vfloat4*>(x);
    vfloat4* __restrict__ ob = reinterpret_cast<vfloat4*>(out);
    const vfloat4 vz = {0.0f, 0.0f, 0.0f, 0.0f};

    int t = blockIdx.x;
    if (t >= ntiles) return;

    vfloat4 st[NLD];                    // staging regs = second buffer

    // ---- Prologue: load tile t -> regs -> LDS ----
    {
        int base = t * TF4;
        #pragma unroll
        for (int k = 0; k < NLD; ++k) {
            int f = k * 64 + lane;
            st[k] = (f < TF4 && base + f < total_f4) ? xb[base + f] : vz;
        }
        #pragma unroll
        for (int k = 0; k < NLD; ++k) {
            int f = k * 64 + lane;
            if (f < TF4) tile[f] = st[k];
        }
    }
    __builtin_amdgcn_sched_barrier(0);

    for (; t < ntiles; t += GRID) {
        const int tn = t + GRID;

        // 1) issue NEXT tile's loads first; results land in st[] later.
        if (tn < ntiles) {
            int base = tn * TF4;
            #pragma unroll
            for (int k = 0; k < NLD; ++k) {
                int f = k * 64 + lane;
                st[k] = (f < TF4 && base + f < total_f4) ? xb[base + f] : vz;
            }
        }
        __builtin_amdgcn_sched_barrier(0);

        // 2) walk current tile: serial 100-step LIF per row, lanes 0..31.
        if (lane < TROWS) {
            unsigned int pk0 = 0, pk1 = 0, pk2 = 0, pk3 = 0;
            float v = 0.0f;
            #pragma unroll
            for (int c = 0; c < T_VEC; ++c) {
                vfloat4 xs = tile[lane * T_VEC + c];   // (r+c)%8 quad: even spread
                #pragma unroll
                for (int k = 0; k < 4; ++k) {
                    // v*0.5 exact (pow2); s*0.5 in {0,0.5} exact -> bitwise == ref.
                    v = v * DECAY + xs[k];
                    bool s = (v - VTH > 0.0f);
                    v -= s ? VTH : 0.0f;
                    unsigned int bit = s ? 1u : 0u;
                    const int b = c * 4 + k;           // compile-time 0..99
                    if      (b < 32) pk0 |= bit << b;
                    else if (b < 64) pk1 |= bit << (b - 32);
                    else if (b < 96) pk2 |= bit << (b - 64);
                    else             pk3 |= bit << (b - 96);
                }
            }
            uint4 w; w.x = pk0; w.y = pk1; w.z = pk2; w.w = pk3;
            bitsbuf[lane] = w;                         // in-wave DS order
        }
        __builtin_amdgcn_sched_barrier(0);

        // 3) expand + store current tile (all 64 lanes, coalesced 1KB instrs).
        {
            int base = t * TF4;
            #pragma unroll
            for (int i = 0; i < NLD; ++i) {
                int lf = i * 64 + lane;
                if (lf < TF4 && base + lf < total_f4) {
                    int r  = lf / T_VEC;               // magic-mul
                    int c4 = lf % T_VEC;
                    unsigned int word =
                        reinterpret_cast<const unsigned int*>(bitsbuf)[r * 4 + (c4 >> 3)];
                    unsigned int nib = (word >> ((c4 & 7) * 4)) & 0xFu;
                    vfloat4 s;
                    s.x = (nib & 1u) ? 1.0f : 0.0f;
                    s.y = (nib & 2u) ? 1.0f : 0.0f;
                    s.z = (nib & 4u) ? 1.0f : 0.0f;
                    s.w = (nib & 8u) ? 1.0f : 0.0f;
                    ob[base + lf] = s;
                }
            }
        }
        __builtin_amdgcn_sched_barrier(0);

        // 4) stage next tile into LDS. Compiler emits its own counted vmcnt
        //    before the first dependent ds_write; WAR vs step-2/3 reads is
        //    safe via the wave's in-order DS pipe + pinned emission order.
        if (tn < ntiles) {
            #pragma unroll
            for (int k = 0; k < NLD; ++k) {
                int f = k * 64 + lane;
                if (f < TF4) tile[f] = st[k];
            }
        }
        __builtin_amdgcn_sched_barrier(0);
    }
}

extern "C" void kernel_launch(void* const* d_in, const int* in_sizes, int n_in,
                              void* d_out, int out_size, void* d_ws, size_t ws_size,
                              hipStream_t stream) {
    const float* x = (const float*)d_in[0];
    float* out = (float*)d_out;

    int n_rows = in_sizes[0] / T_STEPS;                // 32 * 16384 = 524288
    int ntiles = (n_rows + TROWS - 1) / TROWS;         // 16384
    int grid = (ntiles < GRID) ? ntiles : GRID;        // 3072 persistent blocks

    lif_pipe<<<grid, 64, 0, stream>>>(x, out, n_rows);
}